// Round 1
// baseline (1258.684 us; speedup 1.0000x reference)
//
#include <hip/hip_runtime.h>
#include <stdint.h>

typedef unsigned short u16;
typedef short short8 __attribute__((ext_vector_type(8)));
typedef short short4v __attribute__((ext_vector_type(4)));
typedef float f32x4 __attribute__((ext_vector_type(4)));

#define DEV static __device__ __forceinline__

DEV u16 f2bf(float x) {
    union { float f; uint32_t u; } v; v.f = x;
    uint32_t r = v.u + 0x7FFFu + ((v.u >> 16) & 1u);   // RNE
    return (u16)(r >> 16);
}
DEV float bf2f(u16 h) {
    union { uint32_t u; float f; } v; v.u = ((uint32_t)h) << 16;
    return v.f;
}

// async global->LDS, 16B per lane; LDS dest is wave-uniform base + lane*16 (guide m104)
DEV void gload_lds16(const u16* g, u16* l) {
    __builtin_amdgcn_global_load_lds(
        (__attribute__((address_space(1))) void*)g,
        (__attribute__((address_space(3))) void*)l, 16, 0, 0);
}

enum { F_RELU = 1, F_ACCUM = 2, F_CSKIP = 4, F_CKLIM = 8 };

// C[M,N] = A[M,K] (bf16, row-major, lda) @ B^T where B is stored [N,K] (bf16, row-major, ldb)
// epilogue: v = acc*scale + bias[c]; relu; accum(+= Cf); write Cf (f32) and/or Cb (bf16)
__global__ __launch_bounds__(256, 2)
void gemm_bt(const u16* __restrict__ A, const u16* __restrict__ B,
             float* __restrict__ Cf, u16* __restrict__ Cb,
             const float* __restrict__ bias,
             int M, int N, int K, int lda, int ldb, int ldc,
             long long sA, long long sB, long long sC,
             float scale, int flags)
{
    const int tm = blockIdx.x, tn = blockIdx.y, bz = blockIdx.z;
    if ((flags & F_CSKIP) && tn > tm) return;      // causal: skip strictly-upper tiles
    A += (long long)bz * sA;
    B += (long long)bz * sB;
    const long long coff = (long long)bz * sC;

    __shared__ u16 As[128 * 32];   // [row][k], linear for global_load_lds
    __shared__ u16 Bs[128 * 32];   // [n][k]   (B^T layout)

    const int tid = threadIdx.x;
    const int lane = tid & 63, w = tid >> 6;
    const int wr = w >> 1, wc = w & 1;             // 2x2 wave grid, 64x64 per wave
    const int l15 = lane & 15, l4 = lane >> 4;

    f32x4 acc[4][4];
    const f32x4 z4 = {0.f, 0.f, 0.f, 0.f};
#pragma unroll
    for (int m = 0; m < 4; ++m)
#pragma unroll
        for (int n = 0; n < 4; ++n) acc[m][n] = z4;

    int kend = K;
    if (flags & F_CKLIM) { int ke = (tm + 1) * 128; if (ke < kend) kend = ke; }

    const u16* Abase = A + (long long)tm * 128 * lda;
    const u16* Bbase = B + (long long)tn * 128 * ldb;

    for (int k0 = 0; k0 < kend; k0 += 32) {
        // stage 8KB A + 8KB B: each wave 2 issues of 1KB each per operand
#pragma unroll
        for (int i = 0; i < 2; ++i) {
            const int e0 = (i * 4 + w) * 512;      // element offset of this wave's 1KB chunk
            const int e  = e0 + lane * 8;
            const int row = e >> 5, col = e & 31;
            gload_lds16(Abase + (long long)row * lda + (k0 + col), (u16*)As + e0);
            gload_lds16(Bbase + (long long)row * ldb + (k0 + col), (u16*)Bs + e0);
        }
        __syncthreads();

        short8 af[4], bfr[4];
#pragma unroll
        for (int m = 0; m < 4; ++m)
            af[m] = *(const short8*)&As[(wr * 64 + m * 16 + l15) * 32 + l4 * 8];
#pragma unroll
        for (int n = 0; n < 4; ++n)
            bfr[n] = *(const short8*)&Bs[(wc * 64 + n * 16 + l15) * 32 + l4 * 8];
#pragma unroll
        for (int m = 0; m < 4; ++m)
#pragma unroll
            for (int n = 0; n < 4; ++n)
                acc[m][n] = __builtin_amdgcn_mfma_f32_16x16x32_bf16(af[m], bfr[n], acc[m][n], 0, 0, 0);
        __syncthreads();
    }

    // epilogue — C/D layout: col = lane&15, row = (lane>>4)*4 + reg (verified m89/m91)
#pragma unroll
    for (int n = 0; n < 4; ++n) {
        const int c = tn * 128 + wc * 64 + n * 16 + l15;
        const float bv = bias ? bias[c] : 0.0f;
#pragma unroll
        for (int m = 0; m < 4; ++m) {
            const int r0 = tm * 128 + wr * 64 + m * 16 + l4 * 4;
#pragma unroll
            for (int j = 0; j < 4; ++j) {
                float v = acc[m][n][j] * scale + bv;
                if (flags & F_RELU) v = fmaxf(v, 0.0f);
                const long long off = coff + (long long)(r0 + j) * ldc + c;
                if (flags & F_ACCUM) v += Cf[off];
                if (Cf) Cf[off] = v;
                if (Cb) Cb[off] = f2bf(v);
            }
        }
    }
}

// in [R,C] f32 -> out [C,R] bf16
__global__ void transpose_f2b(const float* __restrict__ in, u16* __restrict__ out, int R, int C)
{
    __shared__ float tile[32][33];
    const int tx = threadIdx.x, ty = threadIdx.y;   // (32,8)
    const int gx = blockIdx.x, gy = blockIdx.y;
#pragma unroll
    for (int i = 0; i < 4; ++i)
        tile[ty + i * 8][tx] = in[(long long)(gy * 32 + ty + i * 8) * C + gx * 32 + tx];
    __syncthreads();
#pragma unroll
    for (int i = 0; i < 4; ++i)
        out[(long long)(gx * 32 + ty + i * 8) * R + gy * 32 + tx] = f2bf(tile[tx][ty + i * 8]);
}

// in [R,C] bf16 -> out [C,R] bf16, batched via z
__global__ void transpose_b2b(const u16* __restrict__ in, u16* __restrict__ out,
                              int R, int C, long long sIn, long long sOut)
{
    __shared__ u16 tile[32][34];
    in  += (long long)blockIdx.z * sIn;
    out += (long long)blockIdx.z * sOut;
    const int tx = threadIdx.x, ty = threadIdx.y;
    const int gx = blockIdx.x, gy = blockIdx.y;
#pragma unroll
    for (int i = 0; i < 4; ++i)
        tile[ty + i * 8][tx] = in[(long long)(gy * 32 + ty + i * 8) * C + gx * 32 + tx];
    __syncthreads();
#pragma unroll
    for (int i = 0; i < 4; ++i)
        out[(long long)(gx * 32 + ty + i * 8) * R + gy * 32 + tx] = tile[tx][ty + i * 8];
}

__global__ __launch_bounds__(256)
void embed_kernel(const int* __restrict__ x, const float* __restrict__ emb,
                  const float* __restrict__ pos, float* __restrict__ h32, u16* __restrict__ hbf)
{
    const long long row = blockIdx.x;                 // b*T + t
    const int t = (int)(row & 2047);
    const int idx = x[row];
    const int tid = threadIdx.x;
    const float4 e = ((const float4*)(emb + (long long)idx * 1024))[tid];
    const float4 p = ((const float4*)(pos + (long long)t * 1024))[tid];
    float y0 = e.x + p.x, y1 = e.y + p.y, y2 = e.z + p.z, y3 = e.w + p.w;
    float4 o; o.x = y0; o.y = y1; o.z = y2; o.w = y3;
    ((float4*)(h32 + row * 1024))[tid] = o;
    short4v ob = { (short)f2bf(y0), (short)f2bf(y1), (short)f2bf(y2), (short)f2bf(y3) };
    *(short4v*)(hbf + row * 1024 + tid * 4) = ob;
}

// o = LN(a+b)*gamma + beta over D=1024; writes f32 and bf16 copies. In-place-safe per row.
__global__ __launch_bounds__(256)
void ln_kernel(const float* __restrict__ a, const float* __restrict__ b,
               const float* __restrict__ gamma, const float* __restrict__ beta,
               float* __restrict__ o32, u16* __restrict__ obf)
{
    const long long row = blockIdx.x;
    const int tid = threadIdx.x, lane = tid & 63, w = tid >> 6;
    const float4 xa = ((const float4*)(a + row * 1024))[tid];
    const float4 xb = ((const float4*)(b + row * 1024))[tid];
    float x0 = xa.x + xb.x, x1 = xa.y + xb.y, x2 = xa.z + xb.z, x3 = xa.w + xb.w;
    float s = x0 + x1 + x2 + x3;
    float q = x0 * x0 + x1 * x1 + x2 * x2 + x3 * x3;
#pragma unroll
    for (int o = 32; o; o >>= 1) { s += __shfl_xor(s, o, 64); q += __shfl_xor(q, o, 64); }
    __shared__ float red[8];
    if (lane == 0) { red[w] = s; red[4 + w] = q; }
    __syncthreads();
    s = red[0] + red[1] + red[2] + red[3];
    q = red[4] + red[5] + red[6] + red[7];
    const float mu = s * (1.0f / 1024.0f);
    const float var = q * (1.0f / 1024.0f) - mu * mu;
    const float rs = rsqrtf(var + 1e-5f);
    const float4 g  = ((const float4*)gamma)[tid];
    const float4 be = ((const float4*)beta)[tid];
    float y0 = (x0 - mu) * rs * g.x + be.x;
    float y1 = (x1 - mu) * rs * g.y + be.y;
    float y2 = (x2 - mu) * rs * g.z + be.z;
    float y3 = (x3 - mu) * rs * g.w + be.w;
    float4 o; o.x = y0; o.y = y1; o.z = y2; o.w = y3;
    ((float4*)(o32 + row * 1024))[tid] = o;
    short4v ob = { (short)f2bf(y0), (short)f2bf(y1), (short)f2bf(y2), (short)f2bf(y3) };
    *(short4v*)(obf + row * 1024 + tid * 4) = ob;
}

// in-place causal softmax on bf16 S rows of length T=2048; row = b*T + t
__global__ __launch_bounds__(256)
void softmax_causal(u16* __restrict__ SP)
{
    const long long row = blockIdx.x;
    const int t = (int)(row & 2047);
    u16* p = SP + row * 2048;
    const int tid = threadIdx.x, lane = tid & 63, w = tid >> 6;

    short8 v = *(const short8*)&p[tid * 8];
    float x[8];
#pragma unroll
    for (int j = 0; j < 8; ++j) {
        const int c = tid * 8 + j;
        x[j] = (c <= t) ? bf2f((u16)v[j]) : -1e30f;
    }
    float mx = x[0];
#pragma unroll
    for (int j = 1; j < 8; ++j) mx = fmaxf(mx, x[j]);
#pragma unroll
    for (int o = 32; o; o >>= 1) mx = fmaxf(mx, __shfl_xor(mx, o, 64));
    __shared__ float red[8];
    if (lane == 0) red[w] = mx;
    __syncthreads();
    mx = fmaxf(fmaxf(red[0], red[1]), fmaxf(red[2], red[3]));

    float s = 0.f;
#pragma unroll
    for (int j = 0; j < 8; ++j) {
        const float e = (tid * 8 + j <= t) ? exp2f((x[j] - mx) * 1.44269504f) : 0.f;
        x[j] = e; s += e;
    }
#pragma unroll
    for (int o = 32; o; o >>= 1) s += __shfl_xor(s, o, 64);
    if (lane == 0) red[4 + w] = s;
    __syncthreads();
    s = red[4] + red[5] + red[6] + red[7];
    const float inv = 1.0f / s;

    short8 ov;
#pragma unroll
    for (int j = 0; j < 8; ++j) ov[j] = (short)f2bf(x[j] * inv);
    *(short8*)&p[tid * 8] = ov;
}

extern "C" void kernel_launch(void* const* d_in, const int* in_sizes, int n_in,
                              void* d_out, int out_size, void* d_ws, size_t ws_size,
                              hipStream_t stream)
{
    (void)in_sizes; (void)n_in; (void)out_size; (void)ws_size;
    const int Dd = 1024, T_ = 2048, B_ = 4, NLl = 2, M = B_ * T_;   // M = 8192
    const float inv_sqrt_d = 0.03125f;                              // 1/sqrt(1024)

    const int*   x     = (const int*)  d_in[0];
    const float* emb   = (const float*)d_in[1];
    const float* pos   = (const float*)d_in[2];
    const float* wq    = (const float*)d_in[3];
    const float* wk    = (const float*)d_in[4];
    const float* wv    = (const float*)d_in[5];
    const float* wo    = (const float*)d_in[6];
    const float* wup   = (const float*)d_in[7];
    const float* bup   = (const float*)d_in[8];
    const float* wdown = (const float*)d_in[9];
    const float* bdown = (const float*)d_in[10];
    const float* ga    = (const float*)d_in[11];
    const float* ba    = (const float*)d_in[12];
    const float* gm    = (const float*)d_in[13];
    const float* bm    = (const float*)d_in[14];

    char* ws = (char*)d_ws;
    size_t off = 0;
    auto alloc = [&](size_t bytes) -> void* {
        void* p = ws + off; off += (bytes + 255) & ~(size_t)255; return p;
    };
    float* h32  = (float*)alloc((size_t)M * Dd * 4);
    u16*   hbf  = (u16*)  alloc((size_t)M * Dd * 2);
    float* z32  = (float*)alloc((size_t)M * Dd * 4);
    u16*   qbf  = (u16*)  alloc((size_t)M * Dd * 2);   // q, later attn-out
    u16*   kbf  = (u16*)  alloc((size_t)M * Dd * 2);
    u16*   vbf  = (u16*)  alloc((size_t)M * Dd * 2);
    u16*   vtbf = (u16*)  alloc((size_t)M * Dd * 2);   // per-batch [D,T]
    u16*   SP   = (u16*)  alloc((size_t)B_ * T_ * T_ * 2);   // S then P in place
    u16*   ubf  = (u16*)  alloc((size_t)M * 2048 * 2);       // MLP chunk
    u16*   wtb  = (u16*)  alloc((size_t)12 * 1024 * 1024 * 2); // transposed weights (per layer)

    u16* wq_t    = wtb;
    u16* wk_t    = wtb + 1 * 1048576;
    u16* wv_t    = wtb + 2 * 1048576;
    u16* wo_t    = wtb + 3 * 1048576;
    u16* wup_t   = wtb + 4 * 1048576;   // [4096,1024]
    u16* wdown_t = wtb + 8 * 1048576;   // [1024,4096]

    dim3 blk(256);
    dim3 tblk(32, 8);

    embed_kernel<<<M, blk, 0, stream>>>(x, emb, pos, h32, hbf);

    for (int l = 0; l < NLl; ++l) {
        const float* wq_l    = wq    + (size_t)l * Dd * Dd;
        const float* wk_l    = wk    + (size_t)l * Dd * Dd;
        const float* wv_l    = wv    + (size_t)l * Dd * Dd;
        const float* wo_l    = wo    + (size_t)l * Dd * Dd;
        const float* wup_l   = wup   + (size_t)l * Dd * 4096;
        const float* wdown_l = wdown + (size_t)l * 4096 * Dd;

        transpose_f2b<<<dim3(32, 32),  tblk, 0, stream>>>(wq_l, wq_t, 1024, 1024);
        transpose_f2b<<<dim3(32, 32),  tblk, 0, stream>>>(wk_l, wk_t, 1024, 1024);
        transpose_f2b<<<dim3(32, 32),  tblk, 0, stream>>>(wv_l, wv_t, 1024, 1024);
        transpose_f2b<<<dim3(32, 32),  tblk, 0, stream>>>(wo_l, wo_t, 1024, 1024);
        transpose_f2b<<<dim3(128, 32), tblk, 0, stream>>>(wup_l, wup_t, 1024, 4096);
        transpose_f2b<<<dim3(32, 128), tblk, 0, stream>>>(wdown_l, wdown_t, 4096, 1024);

        // QKV (q pre-scaled by 1/sqrt(D))
        gemm_bt<<<dim3(64, 8, 1), blk, 0, stream>>>(hbf, wq_t, nullptr, qbf, nullptr,
            M, 1024, 1024, 1024, 1024, 1024, 0, 0, 0, inv_sqrt_d, 0);
        gemm_bt<<<dim3(64, 8, 1), blk, 0, stream>>>(hbf, wk_t, nullptr, kbf, nullptr,
            M, 1024, 1024, 1024, 1024, 1024, 0, 0, 0, 1.0f, 0);
        gemm_bt<<<dim3(64, 8, 1), blk, 0, stream>>>(hbf, wv_t, nullptr, vbf, nullptr,
            M, 1024, 1024, 1024, 1024, 1024, 0, 0, 0, 1.0f, 0);

        // V^T per batch: [T,D] -> [D,T]
        transpose_b2b<<<dim3(32, 64, 4), tblk, 0, stream>>>(vbf, vtbf, 2048, 1024,
            (long long)T_ * Dd, (long long)T_ * Dd);

        // S = Q K^T (causal tile skip), bf16 out
        gemm_bt<<<dim3(16, 16, 4), blk, 0, stream>>>(qbf, kbf, nullptr, SP, nullptr,
            2048, 2048, 1024, 1024, 1024, 2048,
            (long long)T_ * Dd, (long long)T_ * Dd, (long long)T_ * T_, 1.0f, F_CSKIP);

        softmax_causal<<<B_ * T_, blk, 0, stream>>>(SP);

        // attn = P V  (K-limit per row tile); reuse qbf as attn-out
        gemm_bt<<<dim3(16, 8, 4), blk, 0, stream>>>(SP, vtbf, nullptr, qbf, nullptr,
            2048, 1024, 2048, 2048, 2048, 1024,
            (long long)T_ * T_, (long long)Dd * T_, (long long)T_ * Dd, 1.0f, F_CKLIM);

        // z = attn @ wo
        gemm_bt<<<dim3(64, 8, 1), blk, 0, stream>>>(qbf, wo_t, z32, nullptr, nullptr,
            M, 1024, 1024, 1024, 1024, 1024, 0, 0, 0, 1.0f, 0);

        // h = LN(residual + z)
        ln_kernel<<<M, blk, 0, stream>>>(h32, z32, ga + (size_t)l * Dd, ba + (size_t)l * Dd, h32, hbf);

        // MLP in two K/N chunks of 2048 (chunk 1 accumulates into z32)
        for (int c = 0; c < 2; ++c) {
            gemm_bt<<<dim3(64, 16, 1), blk, 0, stream>>>(hbf, wup_t + (size_t)c * 2048 * 1024,
                nullptr, ubf, bup + (size_t)l * 4096 + c * 2048,
                M, 2048, 1024, 1024, 1024, 2048, 0, 0, 0, 1.0f, F_RELU);
            gemm_bt<<<dim3(64, 8, 1), blk, 0, stream>>>(ubf, wdown_t + (size_t)c * 2048,
                z32, nullptr, (c == 0) ? (bdown + (size_t)l * Dd) : nullptr,
                M, 1024, 2048, 2048, 4096, 1024, 0, 0, 0, 1.0f, (c == 0) ? 0 : F_ACCUM);
        }

        // h = LN(h + m); final layer writes d_out (f32)
        float* lnout = (l == NLl - 1) ? (float*)d_out : h32;
        ln_kernel<<<M, blk, 0, stream>>>(h32, z32, gm + (size_t)l * Dd, bm + (size_t)l * Dd, lnout, hbf);
    }
}

// Round 2
// 1201.616 us; speedup vs baseline: 1.0475x; 1.0475x over previous
//
#include <hip/hip_runtime.h>
#include <stdint.h>

typedef unsigned short u16;
typedef short short8 __attribute__((ext_vector_type(8)));
typedef short short4v __attribute__((ext_vector_type(4)));
typedef float f32x4 __attribute__((ext_vector_type(4)));

#define DEV static __device__ __forceinline__

DEV u16 f2bf(float x) {
    union { float f; uint32_t u; } v; v.f = x;
    uint32_t r = v.u + 0x7FFFu + ((v.u >> 16) & 1u);   // RNE
    return (u16)(r >> 16);
}
DEV float bf2f(u16 h) {
    union { uint32_t u; float f; } v; v.u = ((uint32_t)h) << 16;
    return v.f;
}

// async global->LDS, 16B per lane; LDS dest is wave-uniform base + lane*16 (guide m104)
DEV void gload_lds16(const u16* g, u16* l) {
    __builtin_amdgcn_global_load_lds(
        (__attribute__((address_space(1))) void*)g,
        (__attribute__((address_space(3))) void*)l, 16, 0, 0);
}

enum { F_RELU = 1, F_ACCUM = 2, F_CSKIP = 4, F_CKLIM = 8 };

// ---------------------------------------------------------------------------
// m97-structure 128x128 GEMM (proven): C = A[M,K] @ B^T, B stored [N,K]
// ---------------------------------------------------------------------------
__global__ __launch_bounds__(256, 2)
void gemm_bt(const u16* __restrict__ A, const u16* __restrict__ B,
             float* __restrict__ Cf, u16* __restrict__ Cb,
             const float* __restrict__ bias,
             int M, int N, int K, int lda, int ldb, int ldc,
             long long sA, long long sB, long long sC,
             float scale, int flags)
{
    const int tm = blockIdx.x, tn = blockIdx.y, bz = blockIdx.z;
    if ((flags & F_CSKIP) && tn > tm) return;
    A += (long long)bz * sA;
    B += (long long)bz * sB;
    const long long coff = (long long)bz * sC;

    __shared__ u16 As[128 * 32];
    __shared__ u16 Bs[128 * 32];

    const int tid = threadIdx.x;
    const int lane = tid & 63, w = tid >> 6;
    const int wr = w >> 1, wc = w & 1;
    const int l15 = lane & 15, l4 = lane >> 4;

    f32x4 acc[4][4];
    const f32x4 z4 = {0.f, 0.f, 0.f, 0.f};
#pragma unroll
    for (int m = 0; m < 4; ++m)
#pragma unroll
        for (int n = 0; n < 4; ++n) acc[m][n] = z4;

    int kend = K;
    if (flags & F_CKLIM) { int ke = (tm + 1) * 128; if (ke < kend) kend = ke; }

    const u16* Abase = A + (long long)tm * 128 * lda;
    const u16* Bbase = B + (long long)tn * 128 * ldb;

    for (int k0 = 0; k0 < kend; k0 += 32) {
#pragma unroll
        for (int i = 0; i < 2; ++i) {
            const int e0 = (i * 4 + w) * 512;
            const int e  = e0 + lane * 8;
            const int row = e >> 5, col = e & 31;
            gload_lds16(Abase + (long long)row * lda + (k0 + col), (u16*)As + e0);
            gload_lds16(Bbase + (long long)row * ldb + (k0 + col), (u16*)Bs + e0);
        }
        __syncthreads();

        short8 af[4], bfr[4];
#pragma unroll
        for (int m = 0; m < 4; ++m)
            af[m] = *(const short8*)&As[(wr * 64 + m * 16 + l15) * 32 + l4 * 8];
#pragma unroll
        for (int n = 0; n < 4; ++n)
            bfr[n] = *(const short8*)&Bs[(wc * 64 + n * 16 + l15) * 32 + l4 * 8];
#pragma unroll
        for (int m = 0; m < 4; ++m)
#pragma unroll
            for (int n = 0; n < 4; ++n)
                acc[m][n] = __builtin_amdgcn_mfma_f32_16x16x32_bf16(af[m], bfr[n], acc[m][n], 0, 0, 0);
        __syncthreads();
    }

#pragma unroll
    for (int n = 0; n < 4; ++n) {
        const int c = tn * 128 + wc * 64 + n * 16 + l15;
        const float bv = bias ? bias[c] : 0.0f;
#pragma unroll
        for (int m = 0; m < 4; ++m) {
            const int r0 = tm * 128 + wr * 64 + m * 16 + l4 * 4;
#pragma unroll
            for (int j = 0; j < 4; ++j) {
                float v = acc[m][n][j] * scale + bv;
                if (flags & F_RELU) v = fmaxf(v, 0.0f);
                const long long off = coff + (long long)(r0 + j) * ldc + c;
                if (flags & F_ACCUM) v += Cf[off];
                if (Cf) Cf[off] = v;
                if (Cb) Cb[off] = f2bf(v);
            }
        }
    }
}

// ---------------------------------------------------------------------------
// 256x256 8-phase GEMM (T2+T3+T4+T5): Cb = A[M,K] @ B^T (+bias, relu)
// 512 threads = 8 waves (2M x 4N); BK=64; LDS 128KB double-buffered halves.
// ---------------------------------------------------------------------------

// stage one half-tile (128 rows x 64 cols bf16) with inverse-swizzled source,
// linear LDS dest (rule 21).
DEV void stage_half(const u16* __restrict__ g, int ld, u16* l, int tid) {
#pragma unroll
    for (int i = 0; i < 2; ++i) {
        const int oe = (i * 512 + tid) * 8;              // element offset in half-buffer
        const int row = oe >> 6;                          // 64 elems per row
        const int c = (oe & 63) ^ ((row & 7) << 3);       // inverse swizzle (involution)
        gload_lds16(g + (long long)row * ld + c, l + (i * 512 + (tid & ~63)) * 8);
    }
}

#define BAR() do { __builtin_amdgcn_s_barrier(); __builtin_amdgcn_sched_barrier(0); } while (0)
#define WAIT_LGKM0() do { asm volatile("s_waitcnt lgkmcnt(0)" ::: "memory"); __builtin_amdgcn_sched_barrier(0); } while (0)

#define READ_A(H) do {                                                        \
    const u16* _b = As_ + ((t & 1) * 2 + (H)) * 8192;                         \
    _Pragma("unroll") for (int rb = 0; rb < 4; ++rb)                          \
    _Pragma("unroll") for (int ks = 0; ks < 2; ++ks) {                        \
        const int _row = wm * 64 + rb * 16 + l15;                             \
        const int _k = ks * 32 + l4 * 8;                                      \
        af[rb * 2 + ks] = *(const short8*)(_b + _row * 64 + (_k ^ ((_row & 7) << 3))); \
    } } while (0)

#define READ_B(H) do {                                                        \
    const u16* _b = Bs_ + ((t & 1) * 2 + (H)) * 8192;                         \
    _Pragma("unroll") for (int cb2 = 0; cb2 < 2; ++cb2)                       \
    _Pragma("unroll") for (int ks = 0; ks < 2; ++ks) {                        \
        const int _col = wn * 32 + cb2 * 16 + l15;                            \
        const int _k = ks * 32 + l4 * 8;                                      \
        bf[cb2 * 2 + ks] = *(const short8*)(_b + _col * 64 + (_k ^ ((_col & 7) << 3))); \
    } } while (0)

#define MFMA_Q(QM, QN) do {                                                   \
    __builtin_amdgcn_s_setprio(1);                                            \
    _Pragma("unroll") for (int rb = 0; rb < 4; ++rb)                          \
    _Pragma("unroll") for (int cb2 = 0; cb2 < 2; ++cb2)                       \
    _Pragma("unroll") for (int ks = 0; ks < 2; ++ks)                          \
        acc[QM][rb][QN][cb2] = __builtin_amdgcn_mfma_f32_16x16x32_bf16(       \
            af[rb * 2 + ks], bf[cb2 * 2 + ks], acc[QM][rb][QN][cb2], 0, 0, 0);\
    __builtin_amdgcn_s_setprio(0);                                            \
    } while (0)

#define STAGE_A(T, H) stage_half(Abase + (long long)((H) * 128) * lda + (T) * 64, lda, \
                                 As_ + (((T) & 1) * 2 + (H)) * 8192, tid)
#define STAGE_B(T, H) stage_half(Bbase + (long long)((H) * 128) * ldb + (T) * 64, ldb, \
                                 Bs_ + (((T) & 1) * 2 + (H)) * 8192, tid)

__global__ __launch_bounds__(512, 2)
void gemm_bt8(const u16* __restrict__ A, const u16* __restrict__ B,
              u16* __restrict__ Cb, const float* __restrict__ bias,
              int M, int N, int K, int lda, int ldb, int ldc, int flags)
{
    __shared__ u16 lds[65536];                 // 128 KB
    u16* As_ = lds;                            // 4 half-buffers x 8192 elems
    u16* Bs_ = lds + 32768;

    const int tid = threadIdx.x;
    const int lane = tid & 63, w = tid >> 6;
    const int wm = w >> 2, wn = w & 3;         // 2M x 4N wave grid
    const int tm = blockIdx.x, tn = blockIdx.y;
    const int l15 = lane & 15, l4 = lane >> 4;

    const u16* Abase = A + (long long)tm * 256 * lda;
    const u16* Bbase = B + (long long)tn * 256 * ldb;
    const int nt = K >> 6;

    f32x4 acc[2][4][2][2];
    const f32x4 z4 = {0.f, 0.f, 0.f, 0.f};
#pragma unroll
    for (int a = 0; a < 2; ++a)
#pragma unroll
        for (int b = 0; b < 4; ++b)
#pragma unroll
            for (int c = 0; c < 2; ++c)
#pragma unroll
                for (int d = 0; d < 2; ++d) acc[a][b][c][d] = z4;

    // prologue: tile0 fully + tile1 half0s; leave tile1's 4 loads in flight
    STAGE_A(0, 0); STAGE_B(0, 0); STAGE_A(0, 1); STAGE_B(0, 1);
    if (nt > 1) {
        STAGE_A(1, 0); STAGE_B(1, 0);
        asm volatile("s_waitcnt vmcnt(4)" ::: "memory");
    } else {
        asm volatile("s_waitcnt vmcnt(0)" ::: "memory");
    }
    BAR();

    short8 af[8], bf[4];
    for (int t = 0; t < nt; ++t) {
        // phase 0: quadrant (0,0) — reads A-half0,B-half0; stages A1(t+1)
        READ_A(0); READ_B(0);
        if (t + 1 < nt) STAGE_A(t + 1, 1);
        BAR(); WAIT_LGKM0();
        MFMA_Q(0, 0);
        BAR();
        // phase 1: quadrant (0,1) — reuse af; reads B-half1; stages B1(t+1)
        READ_B(1);
        if (t + 1 < nt) STAGE_B(t + 1, 1);
        BAR(); WAIT_LGKM0();
        MFMA_Q(0, 1);
        BAR();
        // phase 2: quadrant (1,0) — reads A-half1,B-half0; stages A0(t+2)
        READ_A(1); READ_B(0);
        if (t + 2 < nt) STAGE_A(t + 2, 0);
        BAR(); WAIT_LGKM0();
        MFMA_Q(1, 0);
        BAR();
        // phase 3: quadrant (1,1) — reuse af; reads B-half1; stages B0(t+2)
        READ_B(1);
        if (t + 2 < nt) STAGE_B(t + 2, 0);
        BAR(); WAIT_LGKM0();
        MFMA_Q(1, 1);
        if (t + 2 < nt) { asm volatile("s_waitcnt vmcnt(4)" ::: "memory"); }
        else            { asm volatile("s_waitcnt vmcnt(0)" ::: "memory"); }
        BAR();
    }

    // epilogue
#pragma unroll
    for (int qn2 = 0; qn2 < 2; ++qn2)
#pragma unroll
    for (int cb2 = 0; cb2 < 2; ++cb2) {
        const int c = tn * 256 + qn2 * 128 + wn * 32 + cb2 * 16 + l15;
        const float bv = bias ? bias[c] : 0.0f;
#pragma unroll
        for (int qm2 = 0; qm2 < 2; ++qm2)
#pragma unroll
        for (int rb = 0; rb < 4; ++rb) {
            const int r0 = tm * 256 + qm2 * 128 + wm * 64 + rb * 16 + l4 * 4;
#pragma unroll
            for (int j = 0; j < 4; ++j) {
                float v = acc[qm2][rb][qn2][cb2][j] + bv;
                if (flags & F_RELU) v = fmaxf(v, 0.0f);
                Cb[(long long)(r0 + j) * ldc + c] = f2bf(v);
            }
        }
    }
}

// ---------------------------------------------------------------------------
// helpers
// ---------------------------------------------------------------------------

// in [R,C] f32 -> out [C,R] bf16, scaled
__global__ void transpose_f2b(const float* __restrict__ in, u16* __restrict__ out,
                              int R, int C, float scale)
{
    __shared__ float tile[32][33];
    const int tx = threadIdx.x, ty = threadIdx.y;   // (32,8)
    const int gx = blockIdx.x, gy = blockIdx.y;
#pragma unroll
    for (int i = 0; i < 4; ++i)
        tile[ty + i * 8][tx] = in[(long long)(gy * 32 + ty + i * 8) * C + gx * 32 + tx];
    __syncthreads();
#pragma unroll
    for (int i = 0; i < 4; ++i)
        out[(long long)(gx * 32 + ty + i * 8) * R + gy * 32 + tx] = f2bf(tile[tx][ty + i * 8] * scale);
}

// in [R,C] bf16 (row stride ldin) -> out [C,R] bf16, batched via z
__global__ void transpose_b2b(const u16* __restrict__ in, u16* __restrict__ out,
                              int R, int C, int ldin, long long sIn, long long sOut)
{
    __shared__ u16 tile[32][34];
    in  += (long long)blockIdx.z * sIn;
    out += (long long)blockIdx.z * sOut;
    const int tx = threadIdx.x, ty = threadIdx.y;
    const int gx = blockIdx.x, gy = blockIdx.y;
#pragma unroll
    for (int i = 0; i < 4; ++i)
        tile[ty + i * 8][tx] = in[(long long)(gy * 32 + ty + i * 8) * ldin + gx * 32 + tx];
    __syncthreads();
#pragma unroll
    for (int i = 0; i < 4; ++i)
        out[(long long)(gx * 32 + ty + i * 8) * R + gy * 32 + tx] = tile[tx][ty + i * 8];
}

__global__ __launch_bounds__(256)
void embed_kernel(const int* __restrict__ x, const float* __restrict__ emb,
                  const float* __restrict__ pos, float* __restrict__ h32, u16* __restrict__ hbf)
{
    const long long row = blockIdx.x;
    const int t = (int)(row & 2047);
    const int idx = x[row];
    const int tid = threadIdx.x;
    const float4 e = ((const float4*)(emb + (long long)idx * 1024))[tid];
    const float4 p = ((const float4*)(pos + (long long)t * 1024))[tid];
    float y0 = e.x + p.x, y1 = e.y + p.y, y2 = e.z + p.z, y3 = e.w + p.w;
    float4 o; o.x = y0; o.y = y1; o.z = y2; o.w = y3;
    ((float4*)(h32 + row * 1024))[tid] = o;
    short4v ob = { (short)f2bf(y0), (short)f2bf(y1), (short)f2bf(y2), (short)f2bf(y3) };
    *(short4v*)(hbf + row * 1024 + tid * 4) = ob;
}

__global__ __launch_bounds__(256)
void ln_kernel(const float* __restrict__ a, const float* __restrict__ b,
               const float* __restrict__ gamma, const float* __restrict__ beta,
               float* __restrict__ o32, u16* __restrict__ obf)
{
    const long long row = blockIdx.x;
    const int tid = threadIdx.x, lane = tid & 63, w = tid >> 6;
    const float4 xa = ((const float4*)(a + row * 1024))[tid];
    const float4 xb = ((const float4*)(b + row * 1024))[tid];
    float x0 = xa.x + xb.x, x1 = xa.y + xb.y, x2 = xa.z + xb.z, x3 = xa.w + xb.w;
    float s = x0 + x1 + x2 + x3;
    float q = x0 * x0 + x1 * x1 + x2 * x2 + x3 * x3;
#pragma unroll
    for (int o = 32; o; o >>= 1) { s += __shfl_xor(s, o, 64); q += __shfl_xor(q, o, 64); }
    __shared__ float red[8];
    if (lane == 0) { red[w] = s; red[4 + w] = q; }
    __syncthreads();
    s = red[0] + red[1] + red[2] + red[3];
    q = red[4] + red[5] + red[6] + red[7];
    const float mu = s * (1.0f / 1024.0f);
    const float var = q * (1.0f / 1024.0f) - mu * mu;
    const float rs = rsqrtf(var + 1e-5f);
    const float4 g  = ((const float4*)gamma)[tid];
    const float4 be = ((const float4*)beta)[tid];
    float y0 = (x0 - mu) * rs * g.x + be.x;
    float y1 = (x1 - mu) * rs * g.y + be.y;
    float y2 = (x2 - mu) * rs * g.z + be.z;
    float y3 = (x3 - mu) * rs * g.w + be.w;
    float4 o; o.x = y0; o.y = y1; o.z = y2; o.w = y3;
    ((float4*)(o32 + row * 1024))[tid] = o;
    short4v ob = { (short)f2bf(y0), (short)f2bf(y1), (short)f2bf(y2), (short)f2bf(y3) };
    *(short4v*)(obf + row * 1024 + tid * 4) = ob;
}

__global__ __launch_bounds__(256)
void softmax_causal(u16* __restrict__ SP)
{
    const long long row = blockIdx.x;
    const int t = (int)(row & 2047);
    u16* p = SP + row * 2048;
    const int tid = threadIdx.x, lane = tid & 63, w = tid >> 6;

    short8 v = *(const short8*)&p[tid * 8];
    float x[8];
#pragma unroll
    for (int j = 0; j < 8; ++j) {
        const int c = tid * 8 + j;
        x[j] = (c <= t) ? bf2f((u16)v[j]) : -1e30f;
    }
    float mx = x[0];
#pragma unroll
    for (int j = 1; j < 8; ++j) mx = fmaxf(mx, x[j]);
#pragma unroll
    for (int o = 32; o; o >>= 1) mx = fmaxf(mx, __shfl_xor(mx, o, 64));
    __shared__ float red[8];
    if (lane == 0) red[w] = mx;
    __syncthreads();
    mx = fmaxf(fmaxf(red[0], red[1]), fmaxf(red[2], red[3]));

    float s = 0.f;
#pragma unroll
    for (int j = 0; j < 8; ++j) {
        const float e = (tid * 8 + j <= t) ? exp2f((x[j] - mx) * 1.44269504f) : 0.f;
        x[j] = e; s += e;
    }
#pragma unroll
    for (int o = 32; o; o >>= 1) s += __shfl_xor(s, o, 64);
    if (lane == 0) red[4 + w] = s;
    __syncthreads();
    s = red[4] + red[5] + red[6] + red[7];
    const float inv = 1.0f / s;

    short8 ov;
#pragma unroll
    for (int j = 0; j < 8; ++j) ov[j] = (short)f2bf(x[j] * inv);
    *(short8*)&p[tid * 8] = ov;
}

extern "C" void kernel_launch(void* const* d_in, const int* in_sizes, int n_in,
                              void* d_out, int out_size, void* d_ws, size_t ws_size,
                              hipStream_t stream)
{
    (void)in_sizes; (void)n_in; (void)out_size; (void)ws_size;
    const int Dd = 1024, T_ = 2048, B_ = 4, NLl = 2, M = B_ * T_;
    const float inv_sqrt_d = 0.03125f;

    const int*   x     = (const int*)  d_in[0];
    const float* emb   = (const float*)d_in[1];
    const float* pos   = (const float*)d_in[2];
    const float* wq    = (const float*)d_in[3];
    const float* wk    = (const float*)d_in[4];
    const float* wv    = (const float*)d_in[5];
    const float* wo    = (const float*)d_in[6];
    const float* wup   = (const float*)d_in[7];
    const float* bup   = (const float*)d_in[8];
    const float* wdown = (const float*)d_in[9];
    const float* bdown = (const float*)d_in[10];
    const float* ga    = (const float*)d_in[11];
    const float* ba    = (const float*)d_in[12];
    const float* gm    = (const float*)d_in[13];
    const float* bm    = (const float*)d_in[14];

    char* ws = (char*)d_ws;
    size_t off = 0;
    auto alloc = [&](size_t bytes) -> void* {
        void* p = ws + off; off += (bytes + 255) & ~(size_t)255; return p;
    };
    float* h32   = (float*)alloc((size_t)M * Dd * 4);
    u16*   hbf   = (u16*)  alloc((size_t)M * Dd * 2);
    float* z32   = (float*)alloc((size_t)M * Dd * 4);
    u16*   qkv   = (u16*)  alloc((size_t)M * 3072 * 2);      // [M,3072] q|k|v
    u16*   abf   = (u16*)  alloc((size_t)M * Dd * 2);        // attn out
    u16*   vtbf  = (u16*)  alloc((size_t)M * Dd * 2);        // per-batch [D,T]
    u16*   SP    = (u16*)  alloc((size_t)B_ * T_ * T_ * 2);
    u16*   ubf   = (u16*)  alloc((size_t)M * 4096 * 2);      // MLP hidden
    u16*   wqkv_t  = (u16*)alloc((size_t)3072 * 1024 * 2);   // [3072,1024]
    u16*   wo_t    = (u16*)alloc((size_t)1024 * 1024 * 2);
    u16*   wup_t   = (u16*)alloc((size_t)4096 * 1024 * 2);   // [4096,1024]
    u16*   wdown_t = (u16*)alloc((size_t)1024 * 4096 * 2);   // [1024,4096]

    dim3 blk(256);
    dim3 blk8(512);
    dim3 tblk(32, 8);

    embed_kernel<<<M, blk, 0, stream>>>(x, emb, pos, h32, hbf);

    for (int l = 0; l < NLl; ++l) {
        const float* wq_l    = wq    + (size_t)l * Dd * Dd;
        const float* wk_l    = wk    + (size_t)l * Dd * Dd;
        const float* wv_l    = wv    + (size_t)l * Dd * Dd;
        const float* wo_l    = wo    + (size_t)l * Dd * Dd;
        const float* wup_l   = wup   + (size_t)l * Dd * 4096;
        const float* wdown_l = wdown + (size_t)l * 4096 * Dd;

        // weight transposes; 1/sqrt(D) folded into W_q
        transpose_f2b<<<dim3(32, 32),  tblk, 0, stream>>>(wq_l, wqkv_t,               1024, 1024, inv_sqrt_d);
        transpose_f2b<<<dim3(32, 32),  tblk, 0, stream>>>(wk_l, wqkv_t + 1024 * 1024, 1024, 1024, 1.0f);
        transpose_f2b<<<dim3(32, 32),  tblk, 0, stream>>>(wv_l, wqkv_t + 2048 * 1024, 1024, 1024, 1.0f);
        transpose_f2b<<<dim3(32, 32),  tblk, 0, stream>>>(wo_l, wo_t, 1024, 1024, 1.0f);
        transpose_f2b<<<dim3(128, 32), tblk, 0, stream>>>(wup_l, wup_t, 1024, 4096, 1.0f);
        transpose_f2b<<<dim3(32, 128), tblk, 0, stream>>>(wdown_l, wdown_t, 4096, 1024, 1.0f);

        // fused QKV: [M,1024] @ [3072,1024]^T -> [M,3072]  (8-phase 256^2)
        gemm_bt8<<<dim3(32, 12), blk8, 0, stream>>>(hbf, wqkv_t, qkv, nullptr,
            M, 3072, 1024, 1024, 1024, 3072, 0);

        // V^T per batch: [T,D] (stride 3072) -> [D,T]
        transpose_b2b<<<dim3(32, 64, 4), tblk, 0, stream>>>(qkv + 2048, vtbf, 2048, 1024,
            3072, (long long)T_ * 3072, (long long)Dd * T_);

        // S = Q K^T (causal tile skip)
        gemm_bt<<<dim3(16, 16, 4), blk, 0, stream>>>(qkv, qkv + 1024, nullptr, SP, nullptr,
            2048, 2048, 1024, 3072, 3072, 2048,
            (long long)T_ * 3072, (long long)T_ * 3072, (long long)T_ * T_, 1.0f, F_CSKIP);

        softmax_causal<<<B_ * T_, blk, 0, stream>>>(SP);

        // attn = P V (K-limit per row tile)
        gemm_bt<<<dim3(16, 8, 4), blk, 0, stream>>>(SP, vtbf, nullptr, abf, nullptr,
            2048, 1024, 2048, 2048, 2048, 1024,
            (long long)T_ * T_, (long long)Dd * T_, (long long)T_ * Dd, 1.0f, F_CKLIM);

        // z = attn @ wo
        gemm_bt<<<dim3(64, 8, 1), blk, 0, stream>>>(abf, wo_t, z32, nullptr, nullptr,
            M, 1024, 1024, 1024, 1024, 1024, 0, 0, 0, 1.0f, 0);

        // h = LN(residual + z)
        ln_kernel<<<M, blk, 0, stream>>>(h32, z32, ga + (size_t)l * Dd, ba + (size_t)l * Dd, h32, hbf);

        // MLP up: [M,1024] @ [4096,1024]^T + bias, relu  (8-phase 256^2)
        gemm_bt8<<<dim3(32, 16), blk8, 0, stream>>>(hbf, wup_t, ubf, bup + (size_t)l * 4096,
            M, 4096, 1024, 1024, 1024, 4096, F_RELU);

        // MLP down: [M,4096] @ [1024,4096]^T + bias -> z32 (f32)
        gemm_bt<<<dim3(64, 8, 1), blk, 0, stream>>>(ubf, wdown_t, z32, nullptr,
            bdown + (size_t)l * Dd,
            M, 1024, 4096, 4096, 4096, 1024, 0, 0, 0, 1.0f, 0);

        // h = LN(h + m); final layer writes d_out (f32)
        float* lnout = (l == NLl - 1) ? (float*)d_out : h32;
        ln_kernel<<<M, blk, 0, stream>>>(h32, z32, gm + (size_t)l * Dd, bm + (size_t)l * Dd, lnout, hbf);
    }
}